// Round 13
// baseline (485.520 us; speedup 1.0000x reference)
//
#include <hip/hip_runtime.h>
#include <math.h>

#define NN 50000
#define NE 800000
#define NT 100000           // merged nodes (two graphs)
#define NTP 100032          // padded rows for MFMA gemm
#define ET (2*NE + NT)      // merged CSR entries incl self loops
#define NPB 128             // nodes per bucket
#define NBK 782             // ceil(NT/NPB)
#define BCH 2048            // edges per k_bin chunk
#define BCAP 2816           // k_bucket LDS edge capacity (mean 2048, +17 sigma)

typedef __attribute__((ext_vector_type(8))) short bf16x8;
typedef __attribute__((ext_vector_type(4))) float f32x4;

// ---------- helpers ----------
static __device__ __forceinline__ float wave_max64(float v){
  #pragma unroll
  for(int off=32;off;off>>=1) v = fmaxf(v, __shfl_xor(v,off));
  return v;
}
static __device__ __forceinline__ float wave_sum64(float v){
  #pragma unroll
  for(int off=32;off;off>>=1) v += __shfl_xor(v,off);
  return v;
}
static __device__ __forceinline__ unsigned short f2bf(float f){
  unsigned u = __float_as_uint(f);
  return (unsigned short)((u + 0x7FFFu + ((u>>16)&1u)) >> 16);
}
static __device__ __forceinline__ float bflo(unsigned v){ return __uint_as_float(v<<16); }
static __device__ __forceinline__ float bfhi(unsigned v){ return __uint_as_float(v & 0xFFFF0000u); }

// ---------- bucketed CSR build (bucket = dst>>7) ----------
__global__ __launch_bounds__(256) void k_hist(const int* __restrict__ d1,
    const int* __restrict__ d2, int* __restrict__ bcnt){
  __shared__ int h[1024];
  int t = threadIdx.x;
  #pragma unroll
  for (int i=0;i<4;i++) h[t + i*256] = 0;
  __syncthreads();
  int stride = gridDim.x*256;
  for (int e = blockIdx.x*256 + t; e < NE; e += stride){
    atomicAdd(&h[d1[e]>>7], 1);
    atomicAdd(&h[(d2[e]+NN)>>7], 1);
  }
  __syncthreads();
  #pragma unroll
  for (int i=0;i<4;i++){
    int idx = t + i*256;
    if (h[idx]) atomicAdd(&bcnt[idx], h[idx]);
  }
}

// exclusive scan of bcnt[1024] -> hbase; row_ptr[NT]=ET
__global__ void k_hscan(const int* __restrict__ bcnt, int* __restrict__ hbase,
                        int* __restrict__ row_ptr){
  int t = threadIdx.x;
  int i0 = t*4;
  int c0=bcnt[i0], c1=bcnt[i0+1], c2=bcnt[i0+2], c3=bcnt[i0+3];
  int ts = c0+c1+c2+c3;
  int lane = t & 63, wv = t >> 6;
  int inc = ts;
  #pragma unroll
  for (int off=1; off<64; off<<=1){ int u = __shfl_up(inc, off); if (lane>=off) inc += u; }
  __shared__ int wsum[4];
  if (lane==63) wsum[wv] = inc;
  __syncthreads();
  int woff = 0;
  #pragma unroll
  for (int w=0; w<4; ++w) if (w < wv) woff += wsum[w];
  int run = woff + inc - ts;
  hbase[i0] = run; hbase[i0+1] = run+c0; hbase[i0+2] = run+c0+c1; hbase[i0+3] = run+c0+c1+c2;
  if (t==0) row_ptr[NT] = ET;
}

// block-local counting sort of 2048-edge chunks. pack = src | (dst&127)<<17
__global__ __launch_bounds__(256) void k_bin(const int* __restrict__ s1,
    const int* __restrict__ d1, const float* __restrict__ e1,
    const int* __restrict__ s2, const int* __restrict__ d2,
    const float* __restrict__ e2, const int* __restrict__ hbase,
    int* __restrict__ gcur, uint2* __restrict__ gstage){
  __shared__ int cnt[1024], loff[1024], cur[1024], gbase_sh[1024];
  __shared__ uint2 sdata[BCH];
  __shared__ unsigned short sbkt[BCH];
  __shared__ int wsum[4];
  int tid = threadIdx.x;
  int e0 = blockIdx.x*BCH;
  unsigned pack[8], eab[8];
  unsigned short bk[8];
  #pragma unroll
  for (int i=0;i<4;i++){ cnt[tid + i*256] = 0; cur[tid + i*256] = 0; }
  __syncthreads();
  #pragma unroll
  for (int u=0; u<8; ++u){
    int e = e0 + u*256 + tid;
    int b = NBK; unsigned p = 0, ea = 0;
    if (e < 2*NE){
      int src, dst; float eav;
      if (e < NE){ src = s1[e]; dst = d1[e]; eav = e1[e]; }
      else { int e2i = e - NE; src = s2[e2i] + NN; dst = d2[e2i] + NN; eav = e2[e2i]; }
      b = dst >> 7;
      p = (unsigned)src | ((unsigned)(dst & 127) << 17);
      ea = __float_as_uint(eav);
    }
    bk[u] = (unsigned short)b; pack[u] = p; eab[u] = ea;
    atomicAdd(&cnt[b], 1);
  }
  __syncthreads();
  // exclusive scan cnt[1024] -> loff[1024], 4 per thread
  {
    int i0 = tid*4;
    int c0=cnt[i0], c1=cnt[i0+1], c2=cnt[i0+2], c3=cnt[i0+3];
    int ts = c0+c1+c2+c3;
    int lane = tid & 63, wv = tid >> 6;
    int inc = ts;
    #pragma unroll
    for (int off=1; off<64; off<<=1){ int u = __shfl_up(inc, off); if (lane>=off) inc += u; }
    if (lane==63) wsum[wv] = inc;
    __syncthreads();
    int woff = 0;
    #pragma unroll
    for (int w=0; w<4; ++w) if (w < wv) woff += wsum[w];
    int run = woff + inc - ts;
    loff[i0] = run; loff[i0+1] = run+c0; loff[i0+2] = run+c0+c1; loff[i0+3] = run+c0+c1+c2;
  }
  // reserve global staging ranges
  for (int i = tid; i < NBK; i += 256)
    if (cnt[i] > 0) gbase_sh[i] = hbase[i] + atomicAdd(&gcur[i], cnt[i]);
  __syncthreads();
  // place into LDS, bucket-sorted
  #pragma unroll
  for (int u=0; u<8; ++u){
    int b = bk[u];
    int p = loff[b] + atomicAdd(&cur[b], 1);
    sdata[p] = make_uint2(pack[u], eab[u]);
    sbkt[p] = (unsigned short)b;
  }
  __syncthreads();
  // coalesced flush
  for (int k = tid; k < BCH; k += 256){
    int b = sbkt[k];
    if (b < NBK) gstage[gbase_sh[b] + (k - loff[b])] = sdata[k];
  }
}

// one block per bucket -> final CSR (row_ptr, srt incl self loops)
__global__ __launch_bounds__(256) void k_bucket(const uint2* __restrict__ gstage,
    const int* __restrict__ hbase, int2* __restrict__ srt, int* __restrict__ row_ptr){
  __shared__ uint2 sd[BCAP];
  __shared__ int deg[NPB], rbase[NPB], cur[NPB];
  __shared__ float easum[NPB];
  __shared__ int wsum[4];
  int b = blockIdx.x, t = threadIdx.x;
  int lo = b*NPB;
  int nloc = min(NPB, NT - lo);
  int est = hbase[b], ecnt = hbase[b+1] - est;
  bool inlds = (ecnt <= BCAP);
  if (t < NPB){ deg[t] = 0; easum[t] = 0.f; }
  __syncthreads();
  for (int k = t; k < ecnt; k += 256){
    uint2 v = gstage[est + k];
    if (inlds) sd[k] = v;
    int dl = v.x >> 17;
    atomicAdd(&deg[dl], 1);
    atomicAdd(&easum[dl], __uint_as_float(v.y));
  }
  __syncthreads();
  int dv = (t < nloc) ? deg[t] + 1 : 0;
  int lane = t & 63, wv = t >> 6;
  int inc = dv;
  #pragma unroll
  for (int off=1; off<64; off<<=1){ int u = __shfl_up(inc, off); if (lane>=off) inc += u; }
  if (lane==63) wsum[wv] = inc;
  __syncthreads();
  int woff = 0;
  #pragma unroll
  for (int w=0; w<4; ++w) if (w < wv) woff += wsum[w];
  int gb = est + lo + (woff + inc - dv);
  if (t < nloc){
    row_ptr[lo + t] = gb;
    rbase[t] = gb;
    cur[t] = 1;
    float se = easum[t] / fmaxf((float)deg[t], 1.f);
    srt[gb] = make_int2(lo + t, __float_as_int(se));
  }
  __syncthreads();
  for (int k = t; k < ecnt; k += 256){
    uint2 v = inlds ? sd[k] : gstage[est + k];
    int dl = v.x >> 17;
    int pos = rbase[dl] + atomicAdd(&cur[dl], 1);
    srt[pos] = make_int2((int)(v.x & 0x1FFFFu), (int)v.y);
  }
}

// prep: zero bcnt|gcur|gsum, ce[L] dots, W1/W2 -> bf16 transposed padded Wt[N][136]
__global__ __launch_bounds__(256) void k_prep(
    const float* __restrict__ We0, const float* __restrict__ ae0,
    const float* __restrict__ We1, const float* __restrict__ ae1,
    const float* __restrict__ We2, const float* __restrict__ ae2,
    float* __restrict__ ce3, int* __restrict__ zbase,
    const float* __restrict__ W1, const float* __restrict__ W2,
    unsigned short* __restrict__ Wt1, unsigned short* __restrict__ Wt2){
  int t = threadIdx.x;
  for (int i = t; i < 1024+1024+128; i += 256) zbase[i] = 0;
  if (t < 64){
    const float* We[3] = {We0, We1, We2};
    const float* ae[3] = {ae0, ae1, ae2};
    const int fo[3] = {128, 128, 64};
    for (int L = 0; L < 3; ++L){
      float s = 0.f;
      for (int c = t; c < fo[L]; c += 64) s += We[L][c]*ae[L][c];
      s = wave_sum64(s);
      if (t == 0) ce3[L] = s;
    }
  }
  for (int i = t; i < 128*128; i += 256){
    int c = i >> 7, k = i & 127;
    Wt1[c*136 + k] = f2bf(W1[k*128 + c]);
  }
  for (int i = t; i < 64*128; i += 256){
    int c = i >> 7, k = i & 127;
    Wt2[c*136 + k] = f2bf(W2[k*64 + c]);
  }
}

// ---- MFMA GEMM: h[M,N] = x16[M,128] @ W[128,N] + fused hs/hd + bf16 h16 ----
// 256 rows/block (4 row-tiles per wave), B-fragment reused across row-tiles.
template<int N>
__global__ __launch_bounds__(256) void k_gemm_mfma(
    const unsigned short* __restrict__ x16, const unsigned short* __restrict__ Wt,
    const float* __restrict__ a_src, const float* __restrict__ a_dst,
    unsigned short* __restrict__ h16, float* __restrict__ hs,
    float* __restrict__ hd, int n){
  constexpr int CT = N/16;
  __shared__ unsigned short Wl[N*136];
  int tid = threadIdx.x;
  for (int i = tid; i < N*136/8; i += 256)
    ((uint4*)Wl)[i] = ((const uint4*)Wt)[i];
  __syncthreads();
  int lane = tid & 63, w = tid >> 6;
  int kb   = (lane >> 4) * 8;
  int l15  = lane & 15;
  int rbase0 = blockIdx.x*256 + w*16;
  f32x4 acc[4][CT] = {};
  #pragma unroll
  for (int s = 0; s < 4; ++s){
    bf16x8 a[4];
    #pragma unroll
    for (int rt = 0; rt < 4; ++rt){
      int arow = rbase0 + rt*64 + l15;
      int rsafe = (arow < n) ? arow : (n-1);
      a[rt] = *(const bf16x8*)(x16 + (size_t)rsafe*128 + s*32 + kb);
    }
    #pragma unroll
    for (int c = 0; c < CT; ++c){
      bf16x8 b = *(const bf16x8*)(&Wl[(c*16 + l15)*136 + s*32 + kb]);
      #pragma unroll
      for (int rt = 0; rt < 4; ++rt)
        acc[rt][c] = __builtin_amdgcn_mfma_f32_16x16x32_bf16(a[rt], b, acc[rt][c], 0, 0, 0);
    }
  }
  int dcol = lane & 15;
  #pragma unroll
  for (int rt = 0; rt < 4; ++rt){
    int drow = rbase0 + rt*64 + (lane>>4)*4;
    float psv[4] = {0,0,0,0}, pdv[4] = {0,0,0,0};
    #pragma unroll
    for (int c = 0; c < CT; ++c){
      float as = a_src[c*16 + dcol], ad = a_dst[c*16 + dcol];
      #pragma unroll
      for (int j = 0; j < 4; ++j){
        float v = acc[rt][c][j];
        if (drow + j < n) h16[(size_t)(drow+j)*N + c*16 + dcol] = f2bf(v);
        psv[j] += v*as; pdv[j] += v*ad;
      }
    }
    #pragma unroll
    for (int off = 1; off < 16; off <<= 1){
      #pragma unroll
      for (int j=0;j<4;j++){ psv[j] += __shfl_xor(psv[j], off); pdv[j] += __shfl_xor(pdv[j], off); }
    }
    if (dcol == 0){
      #pragma unroll
      for (int j=0;j<4;j++) if (drow+j < n){ hs[drow+j] = psv[j]; hd[drow+j] = pdv[j]; }
    }
  }
}

// layer-1 GEMM: K=7, N=128
__global__ __launch_bounds__(256) void k_gemm7(const float* __restrict__ x1,
    const float* __restrict__ x2, const float* __restrict__ W,
    const float* __restrict__ a_src, const float* __restrict__ a_dst,
    unsigned short* __restrict__ h16, float* __restrict__ hs,
    float* __restrict__ hd, int n){
  __shared__ float Wl[7][128];
  int tid = threadIdx.x;
  for (int i = tid; i < 7*128; i += 256) ((float*)Wl)[i] = W[i];
  __syncthreads();
  int tx = tid & 31, ty = tid >> 5;
  int r = blockIdx.x*8 + ty;
  if (r >= n) return;
  const float* xr = (r < NN) ? (x1 + (size_t)r*7) : (x2 + (size_t)(r-NN)*7);
  float xv[7];
  #pragma unroll
  for (int k=0;k<7;k++) xv[k] = xr[k];
  float4 s = make_float4(0.f,0.f,0.f,0.f);
  #pragma unroll
  for (int k=0;k<7;k++){
    float4 wv = *(const float4*)(&Wl[k][tx*4]);
    s.x += xv[k]*wv.x; s.y += xv[k]*wv.y; s.z += xv[k]*wv.z; s.w += xv[k]*wv.w;
  }
  unsigned r0p = (unsigned)f2bf(s.x) | ((unsigned)f2bf(s.y)<<16);
  unsigned r1p = (unsigned)f2bf(s.z) | ((unsigned)f2bf(s.w)<<16);
  *(uint2*)(h16 + (size_t)r*128 + tx*4) = make_uint2(r0p, r1p);
  float ps = s.x*a_src[tx*4] + s.y*a_src[tx*4+1] + s.z*a_src[tx*4+2] + s.w*a_src[tx*4+3];
  float pd = s.x*a_dst[tx*4] + s.y*a_dst[tx*4+1] + s.z*a_dst[tx*4+2] + s.w*a_dst[tx*4+3];
  #pragma unroll
  for (int off=16; off; off>>=1){ ps += __shfl_xor(ps, off); pd += __shfl_xor(pd, off); }
  if (tx==0){ hs[r] = ps; hd[r] = pd; }
}

// Per-node fused: alpha -> online softmax -> wide bf16 gather (2-deep,
// uniform tail-skip) -> +b -> ELU
template<int FOUT, bool OBF>
__global__ __launch_bounds__(256) void k_aggregate(const unsigned short* __restrict__ h16,
    const float* __restrict__ hs, const float* __restrict__ hd,
    const int2* __restrict__ srt, const int* __restrict__ row_ptr,
    const float* __restrict__ ce_p, const float* __restrict__ b,
    void* __restrict__ xout, int n){
  constexpr int LPE = FOUT/8;        // lanes per edge (16 or 8)
  constexpr int EPS = 64/LPE;        // edges per step  (4 or 8)
  __shared__ float s_p[4][64];
  __shared__ int   s_s[4][64];
  int tid = threadIdx.x;
  int wv = tid >> 6, lane = tid & 63;
  int wid = (int)((blockIdx.x*256 + tid) >> 6);
  if (wid >= n) return;
  float ce  = *ce_p;
  int beg = row_ptr[wid], end = row_ptr[wid+1];
  float hdn = hd[wid];
  int e_sub = lane / LPE;
  int col8  = (lane % LPE) * 8;
  float m = -INFINITY, den = 0.f;
  float acc[8] = {0.f,0.f,0.f,0.f,0.f,0.f,0.f,0.f};
  for (int base = beg; base < end; base += 64){
    int slot = base + lane;
    float a = -INFINITY; int src = 0;
    if (slot < end){
      int2 pk = srt[slot];
      src = pk.x;
      a = hs[src] + hdn + __int_as_float(pk.y)*ce;
      a = (a > 0.f) ? a : 0.2f*a;
    }
    float cm = wave_max64(a);
    float mnew = fmaxf(m, cm);
    float scale = __expf(m - mnew);
    den *= scale;
    #pragma unroll
    for (int u=0;u<8;u++) acc[u] *= scale;
    float p = __expf(a - mnew);
    den += wave_sum64(p);
    s_p[wv][lane] = p; s_s[wv][lane] = src;
    asm volatile("s_waitcnt lgkmcnt(0)" ::: "memory");
    int cnt = end - base; if (cnt > 64) cnt = 64;
    // p==0 beyond cnt -> rounding up to EPS is safe; second half-group
    // skipped via wave-uniform branch when past cnt.
    for (int j = 0; j < cnt; j += 2*EPS){
      int jj0 = j + e_sub;
      float p0 = s_p[wv][jj0];  int sj0 = s_s[wv][jj0];
      uint4 h0 = *(const uint4*)(h16 + (size_t)sj0*FOUT + col8);
      if (j + EPS < cnt){
        int jj1 = j + EPS + e_sub;
        float p1 = s_p[wv][jj1];  int sj1 = s_s[wv][jj1];
        uint4 h1 = *(const uint4*)(h16 + (size_t)sj1*FOUT + col8);
        acc[0] += p0*bflo(h0.x); acc[1] += p0*bfhi(h0.x);
        acc[2] += p0*bflo(h0.y); acc[3] += p0*bfhi(h0.y);
        acc[4] += p0*bflo(h0.z); acc[5] += p0*bfhi(h0.z);
        acc[6] += p0*bflo(h0.w); acc[7] += p0*bfhi(h0.w);
        acc[0] += p1*bflo(h1.x); acc[1] += p1*bfhi(h1.x);
        acc[2] += p1*bflo(h1.y); acc[3] += p1*bfhi(h1.y);
        acc[4] += p1*bflo(h1.z); acc[5] += p1*bfhi(h1.z);
        acc[6] += p1*bflo(h1.w); acc[7] += p1*bfhi(h1.w);
      } else {
        acc[0] += p0*bflo(h0.x); acc[1] += p0*bfhi(h0.x);
        acc[2] += p0*bflo(h0.y); acc[3] += p0*bfhi(h0.y);
        acc[4] += p0*bflo(h0.z); acc[5] += p0*bfhi(h0.z);
        acc[6] += p0*bflo(h0.w); acc[7] += p0*bfhi(h0.w);
      }
    }
    m = mnew;
  }
  #pragma unroll
  for (int off = LPE; off < 64; off <<= 1){
    #pragma unroll
    for (int u=0;u<8;u++) acc[u] += __shfl_xor(acc[u], off);
  }
  float inv = 1.f/den;
  if (lane < LPE){
    float o[8];
    #pragma unroll
    for (int u=0;u<8;u++){
      o[u] = acc[u]*inv + b[col8+u];
      o[u] = (o[u] > 0.f) ? o[u] : (__expf(o[u]) - 1.f);
    }
    if (OBF){
      uint4 pkd;
      pkd.x = (unsigned)f2bf(o[0]) | ((unsigned)f2bf(o[1])<<16);
      pkd.y = (unsigned)f2bf(o[2]) | ((unsigned)f2bf(o[3])<<16);
      pkd.z = (unsigned)f2bf(o[4]) | ((unsigned)f2bf(o[5])<<16);
      pkd.w = (unsigned)f2bf(o[6]) | ((unsigned)f2bf(o[7])<<16);
      *(uint4*)((unsigned short*)xout + (size_t)wid*FOUT + col8) = pkd;
    } else {
      float4 o0 = make_float4(o[0],o[1],o[2],o[3]);
      float4 o1 = make_float4(o[4],o[5],o[6],o[7]);
      *(float4*)((float*)xout + (size_t)wid*FOUT + col8)     = o0;
      *(float4*)((float*)xout + (size_t)wid*FOUT + col8 + 4) = o1;
    }
  }
}

// column sums over merged x[n,64] fp32
__global__ __launch_bounds__(256) void k_colsum2(const float* __restrict__ x,
    float* __restrict__ gsum, int n){
  __shared__ float ls[128];
  int t = threadIdx.x;
  if (t < 128) ls[t] = 0.f;
  __syncthreads();
  int c4 = (t & 15) * 4;
  int rsub = t >> 4;
  float4 s1 = make_float4(0.f,0.f,0.f,0.f), s2 = make_float4(0.f,0.f,0.f,0.f);
  for (int r = blockIdx.x*16 + rsub; r < n; r += gridDim.x*16){
    float4 v = *(const float4*)(x + (size_t)r*64 + c4);
    if (r < NN){ s1.x+=v.x; s1.y+=v.y; s1.z+=v.z; s1.w+=v.w; }
    else       { s2.x+=v.x; s2.y+=v.y; s2.z+=v.z; s2.w+=v.w; }
  }
  atomicAdd(&ls[c4+0], s1.x); atomicAdd(&ls[c4+1], s1.y);
  atomicAdd(&ls[c4+2], s1.z); atomicAdd(&ls[c4+3], s1.w);
  atomicAdd(&ls[64+c4+0], s2.x); atomicAdd(&ls[64+c4+1], s2.y);
  atomicAdd(&ls[64+c4+2], s2.z); atomicAdd(&ls[64+c4+3], s2.w);
  __syncthreads();
  if (t < 128) atomicAdd(&gsum[t], ls[t]);
}

// final MLP head
__global__ void k_head(const float* __restrict__ gs1, const float* __restrict__ gs2,
                       const float* __restrict__ xn1, const float* __restrict__ xn2,
                       const float* __restrict__ Wlin, const float* __restrict__ blin,
                       const float* __restrict__ Wc1, const float* __restrict__ bc1,
                       const float* __restrict__ Wc2, const float* __restrict__ bc2,
                       float* __restrict__ out){
  __shared__ float c1[80], c2[80], xcat[128], hb[16];
  int tid = threadIdx.x;
  const float invn = 1.f/(float)NN;
  if (tid < 64){ c1[tid] = gs1[tid]*invn; c2[tid] = gs2[tid]*invn; }
  else if (tid < 80){ c1[tid] = xn1[tid-64]; c2[tid] = xn2[tid-64]; }
  __syncthreads();
  if (tid < 64){
    float s = blin[tid];
    for (int k=0;k<80;k++) s += c1[k]*Wlin[k*64+tid];
    xcat[tid] = s;
  } else {
    int j = tid - 64;
    float s = blin[j];
    for (int k=0;k<80;k++) s += c2[k]*Wlin[k*64+j];
    xcat[tid] = s;
  }
  __syncthreads();
  if (tid < 16){
    float s = bc1[tid];
    for (int k=0;k<128;k++) s += xcat[k]*Wc1[k*16+tid];
    hb[tid] = fmaxf(s, 0.f);
  }
  __syncthreads();
  if (tid < 3){
    float s = bc2[tid];
    for (int k=0;k<16;k++) s += hb[k]*Wc2[k*3+tid];
    out[tid] = s;
  }
}

extern "C" void kernel_launch(void* const* d_in, const int* in_sizes, int n_in,
                              void* d_out, int out_size, void* d_ws, size_t ws_size,
                              hipStream_t stream){
  const float* x1  = (const float*)d_in[0];
  const float* x2  = (const float*)d_in[1];
  const int*   ei1 = (const int*)d_in[2];
  const int*   ei2 = (const int*)d_in[3];
  const float* xn1 = (const float*)d_in[4];
  const float* xn2 = (const float*)d_in[5];
  const float* ec1 = (const float*)d_in[6];
  const float* ec2 = (const float*)d_in[7];
  const float* W[3]    = {(const float*)d_in[8],  (const float*)d_in[14], (const float*)d_in[20]};
  const float* asrc[3] = {(const float*)d_in[9],  (const float*)d_in[15], (const float*)d_in[21]};
  const float* adst[3] = {(const float*)d_in[10], (const float*)d_in[16], (const float*)d_in[22]};
  const float* We[3]   = {(const float*)d_in[11], (const float*)d_in[17], (const float*)d_in[23]};
  const float* ae[3]   = {(const float*)d_in[12], (const float*)d_in[18], (const float*)d_in[24]};
  const float* bb[3]   = {(const float*)d_in[13], (const float*)d_in[19], (const float*)d_in[25]};
  const float* Wlin = (const float*)d_in[26];
  const float* blin = (const float*)d_in[27];
  const float* Wc1  = (const float*)d_in[28];
  const float* bc1  = (const float*)d_in[29];
  const float* Wc2  = (const float*)d_in[30];
  const float* bc2  = (const float*)d_in[31];
  float* out = (float*)d_out;

  char* wsb = (char*)d_ws;
  unsigned short* x16   = (unsigned short*)wsb;                  // 25.6 MB (aliased below)
  uint2*          gstage = (uint2*)wsb;                          // alias (CSR build)
  float*          bufX  = (float*)wsb;                           // alias (layer2 out)
  unsigned short* h16  = (unsigned short*)(wsb + (size_t)NTP*128*2);
  int2*           srt  = (int2*)(wsb + (size_t)NTP*128*2 + (size_t)NT*128*2);
  float* hs   = (float*)(srt + ET);               // NT
  float* hd   = hs + NT;                          // NT
  int*   row_ptr = (int*)(hd + NT);               // NT+2
  int*   bcnt  = row_ptr + NT + 2;                // 1024 (zeroed in prep)
  int*   gcur  = bcnt + 1024;                     // 1024 (zeroed in prep)
  float* gsum  = (float*)(gcur + 1024);           // 128 (zeroed in prep)
  int*   hbase = (int*)(gsum + 128);              // 1024
  float* ce3   = (float*)(hbase + 1024);          // 4 (+pad)
  unsigned short* Wt1 = (unsigned short*)(ce3 + 8);   // 128*136
  unsigned short* Wt2 = Wt1 + 128*136;                // 64*136

  const int* s1 = ei1, * d1 = ei1 + NE;
  const int* s2 = ei2, * d2 = ei2 + NE;

  k_prep<<<1, 256, 0, stream>>>(We[0], ae[0], We[1], ae[1], We[2], ae[2], ce3,
                                bcnt, W[1], W[2], Wt1, Wt2);

  // bucketed CSR build
  k_hist<<<256, 256, 0, stream>>>(d1, d2, bcnt);
  k_hscan<<<1, 256, 0, stream>>>(bcnt, hbase, row_ptr);
  k_bin<<<(2*NE + BCH - 1)/BCH, 256, 0, stream>>>(s1, d1, ec1, s2, d2, ec2, hbase, gcur, gstage);
  k_bucket<<<NBK, 256, 0, stream>>>(gstage, hbase, srt, row_ptr);

  // layer 0
  k_gemm7<<<(NT+7)/8, 256, 0, stream>>>(x1, x2, W[0], asrc[0], adst[0], h16, hs, hd, NT);
  k_aggregate<128,true><<<(NT+3)/4, 256, 0, stream>>>(h16, hs, hd, srt, row_ptr, ce3+0, bb[0], x16, NT);
  // layer 1
  k_gemm_mfma<128><<<(NT+255)/256, 256, 0, stream>>>(x16, Wt1, asrc[1], adst[1], h16, hs, hd, NT);
  k_aggregate<128,true><<<(NT+3)/4, 256, 0, stream>>>(h16, hs, hd, srt, row_ptr, ce3+1, bb[1], x16, NT);
  // layer 2
  k_gemm_mfma<64><<<(NT+255)/256, 256, 0, stream>>>(x16, Wt2, asrc[2], adst[2], h16, hs, hd, NT);
  k_aggregate<64,false><<<(NT+3)/4, 256, 0, stream>>>(h16, hs, hd, srt, row_ptr, ce3+2, bb[2], bufX, NT);

  k_colsum2<<<512, 256, 0, stream>>>(bufX, gsum, NT);
  k_head<<<1, 128, 0, stream>>>(gsum, gsum+64, xn1, xn2, Wlin, blin, Wc1, bc1, Wc2, bc2, out);
}